// Round 3
// baseline (456.205 us; speedup 1.0000x reference)
//
#include <hip/hip_runtime.h>

#define B 4
#define L 2048
#define C 64
#define R 8
#define NCH (B * C)      // 256 chains
#define TQ 16            // timesteps per chunk
#define S (L / TQ)       // 128 chunks per chain
#define GRP (NCH / 8)    // 32 chain-groups (8 chains per wave)

// Workspace (float2): sumP [S][NCH][8][8] (16 MB), sumQ [S][NCH][8] (2 MB),
// carry [S][NCH][8] (2 MB).
//
// Lane mapping: lane = c*8 + r (c = chain-in-group, r = row).
// k_summary: 4-wave workgroups; A/X staged direct-to-LDS via
// global_load_lds with PRE-SWIZZLED per-lane global source addresses so the
// linear LDS write (base + lane*16) lands the XOR-swizzled layout:
//   LDS word 64c + 8q + e  holds  A[chain c][row q^c][col e]
// Reads of row k use offset 8*(k^c), spreading the 8 broadcast addresses
// over 4 bank-groups (2-way = free).
// Loads for step t+1 are issued BEFORE compute of step t; counted
// s_waitcnt vmcnt(6) keeps the next step's 6 loads in flight (m97/T3).

#define GLL(gp, lp, sz)                                                        \
    __builtin_amdgcn_global_load_lds(                                          \
        (const __attribute__((address_space(1))) void*)(gp),                   \
        (__attribute__((address_space(3))) void*)(lp), sz, 0, 0)

// ---------------- Phase 1: chunk summaries ----------------
__global__ __launch_bounds__(256) void k_summary(
    const float* __restrict__ Are, const float* __restrict__ Aim,
    const float* __restrict__ Xre, const float* __restrict__ Xim,
    float2* __restrict__ sumP, float2* __restrict__ sumQ)
{
    // per wave: 2 buffers x (A-re 512 + A-im 512 + X-re 64 + X-im 64) floats
    __shared__ __align__(16) float sm[4 * 2 * 1152];   // 36864 B
    const int lane = threadIdx.x & 63;
    const int w = __builtin_amdgcn_readfirstlane((int)(threadIdx.x >> 6));
    const int c = lane >> 3, r = lane & 7;
    const int s = blockIdx.x >> 3;            // chunk
    const int g = (blockIdx.x & 7) * 4 + w;   // chain-group (4 per WG, contiguous)
    const int n0 = g * 8;
    const int b = n0 >> 6;
    const int cc0 = n0 & (C - 1);
    const int n = n0 + c;
    const int tbase = s * TQ;

    // pre-swizzled global float4 offsets for the two A load instructions
    const int q = (lane >> 1) & 7, h = lane & 1;
    const int c0 = lane >> 4, c1 = 4 + (lane >> 4);
    const int o0 = c0 * 16 + ((q ^ c0) << 1) + h;
    const int o1 = c1 * 16 + ((q ^ c1) << 1) + h;

    char* lw = ((char*)sm) + w * 9216;        // wave's LDS base (uniform)
    const float* wb = sm + w * 2304;

    float Pre[8], Pim[8];
#pragma unroll
    for (int k = 0; k < 8; ++k) { Pre[k] = (k == r) ? 1.f : 0.f; Pim[k] = 0.f; }
    float qre = 0.f, qim = 0.f;

#define ISSUE1(t, bf)                                                          \
    {                                                                          \
        const int fb = (b * L + (t)) * C + cc0;                                \
        const float4* gA = (const float4*)(Are + (long)fb * 64);               \
        const float4* gI = (const float4*)(Aim + (long)fb * 64);               \
        char* lb = lw + (bf) * 4608;                                           \
        GLL(gA + o0, lb, 16);                                                  \
        GLL(gA + o1, lb + 1024, 16);                                           \
        GLL(gI + o0, lb + 2048, 16);                                           \
        GLL(gI + o1, lb + 3072, 16);                                           \
        GLL(Xre + (long)fb * 8 + lane, lb + 4096, 4);                          \
        GLL(Xim + (long)fb * 8 + lane, lb + 4352, 4);                          \
    }

#define COMPUTE_STEP1(bp)                                                      \
    {                                                                          \
        float xr[8], xi[8];                                                    \
        *(float4*)&xr[0] = *(const float4*)((bp) + 1024 + c * 8);              \
        *(float4*)&xr[4] = *(const float4*)((bp) + 1024 + c * 8 + 4);          \
        *(float4*)&xi[0] = *(const float4*)((bp) + 1088 + c * 8);              \
        *(float4*)&xi[4] = *(const float4*)((bp) + 1088 + c * 8 + 4);          \
        _Pragma("unroll")                                                      \
        for (int k = 0; k < 8; ++k) {                                          \
            qre += Pre[k] * xr[k] - Pim[k] * xi[k];                            \
            qim += Pre[k] * xi[k] + Pim[k] * xr[k];                            \
        }                                                                      \
        float Nre[8], Nim[8];                                                  \
        _Pragma("unroll")                                                      \
        for (int j = 0; j < 8; ++j) { Nre[j] = 0.f; Nim[j] = 0.f; }            \
        _Pragma("unroll")                                                      \
        for (int k = 0; k < 8; ++k) {                                          \
            const int ko = ((k ^ c) << 3);                                     \
            float er[8], ei[8];                                                \
            *(float4*)&er[0] = *(const float4*)((bp) + c * 64 + ko);           \
            *(float4*)&er[4] = *(const float4*)((bp) + c * 64 + ko + 4);       \
            *(float4*)&ei[0] = *(const float4*)((bp) + 512 + c * 64 + ko);     \
            *(float4*)&ei[4] = *(const float4*)((bp) + 512 + c * 64 + ko + 4); \
            const float pr = Pre[k], pi = Pim[k];                              \
            _Pragma("unroll")                                                  \
            for (int j = 0; j < 8; ++j) {                                      \
                Nre[j] += pr * er[j] - pi * ei[j];                             \
                Nim[j] += pr * ei[j] + pi * er[j];                             \
            }                                                                  \
        }                                                                      \
        _Pragma("unroll")                                                      \
        for (int k = 0; k < 8; ++k) { Pre[k] = Nre[k]; Pim[k] = Nim[k]; }      \
    }

    // backward over t: process t = tbase+TQ-1 down to tbase
    ISSUE1(tbase + TQ - 1, 0);
#pragma unroll 1
    for (int tt = 0; tt < TQ - 1; ++tt) {
        ISSUE1(tbase + TQ - 2 - tt, (tt + 1) & 1);   // next step's loads first
        asm volatile("s_waitcnt vmcnt(6)" ::: "memory");
        __builtin_amdgcn_sched_barrier(0);
        const float* bp = wb + (tt & 1) * 1152;
        COMPUTE_STEP1(bp);
    }
    asm volatile("s_waitcnt vmcnt(0)" ::: "memory");
    __builtin_amdgcn_sched_barrier(0);
    {
        const float* bp = wb + ((TQ - 1) & 1) * 1152;
        COMPUTE_STEP1(bp);
    }

    // store P row r (8 complex) and q
    float4* gp = (float4*)(sumP + ((long)(s * 256 + n) * 8 + r) * 8);
    gp[0] = make_float4(Pre[0], Pim[0], Pre[1], Pim[1]);
    gp[1] = make_float4(Pre[2], Pim[2], Pre[3], Pim[3]);
    gp[2] = make_float4(Pre[4], Pim[4], Pre[5], Pim[5]);
    gp[3] = make_float4(Pre[6], Pim[6], Pre[7], Pim[7]);
    sumQ[(long)(s * 256 + n) * 8 + r] = make_float2(qre, qim);
}

// ---------------- Phase 2: carry scan over chunks ----------------
__global__ __launch_bounds__(64) void k_carry(
    const float2* __restrict__ sumP, const float2* __restrict__ sumQ,
    float2* __restrict__ carry)
{
    const int lane = threadIdx.x;
    const int c = lane >> 3, r = lane & 7;
    const int n = blockIdx.x * 8 + c;

    float yr = 0.f, yi = 0.f;    // carry into chunk 0 is zero
    long base = (long)n * 8;
    const float4* prow0 = (const float4*)(sumP + (base + r) * 8);
    float4 p0 = prow0[0], p1 = prow0[1], p2 = prow0[2], p3 = prow0[3];
    float2 qv = sumQ[base + r];

#pragma unroll 1
    for (int s = 0; s < S; ++s) {
        carry[base + r] = make_float2(yr, yi);
        // broadcast carry vector within chain group via shuffles (pipelined)
        float yvr[8], yvi[8];
#pragma unroll
        for (int k = 0; k < 8; ++k) {
            yvr[k] = __shfl(yr, (c << 3) + k, 64);
            yvi[k] = __shfl(yi, (c << 3) + k, 64);
        }
        float4 w0 = p0, w1 = p1, w2 = p2, w3 = p3;
        float2 qq = qv;
        if (s + 1 < S) {
            const long nb = base + 2048;
            const float4* np = (const float4*)(sumP + (nb + r) * 8);
            p0 = np[0]; p1 = np[1]; p2 = np[2]; p3 = np[3];
            qv = sumQ[nb + r];
        }
        float prr[8], pri[8];
        prr[0]=w0.x; pri[0]=w0.y; prr[1]=w0.z; pri[1]=w0.w;
        prr[2]=w1.x; pri[2]=w1.y; prr[3]=w1.z; pri[3]=w1.w;
        prr[4]=w2.x; pri[4]=w2.y; prr[5]=w2.z; pri[5]=w2.w;
        prr[6]=w3.x; pri[6]=w3.y; prr[7]=w3.z; pri[7]=w3.w;
        float nr0 = qq.x, ni0 = qq.y, nr1 = 0.f, ni1 = 0.f;
#pragma unroll
        for (int k = 0; k < 8; k += 2) {
            nr0 += prr[k] * yvr[k] - pri[k] * yvi[k];
            ni0 += prr[k] * yvi[k] + pri[k] * yvr[k];
            nr1 += prr[k+1] * yvr[k+1] - pri[k+1] * yvi[k+1];
            ni1 += prr[k+1] * yvi[k+1] + pri[k+1] * yvr[k+1];
        }
        yr = nr0 + nr1; yi = ni0 + ni1;
        base += 2048;
    }
}

// ---------------- Phase 3: fixup + output ----------------
// Lane (c,r) only needs its OWN row r of A_t (register prefetch, no LDS).
// The per-step carry broadcast uses __shfl (one bpermute latency on the
// serial chain instead of an LDS write->read round trip).
__global__ __launch_bounds__(256) void k_fixup(
    const float* __restrict__ Are, const float* __restrict__ Aim,
    const float* __restrict__ Xre, const float* __restrict__ Xim,
    const float2* __restrict__ carry, float2* __restrict__ out)
{
    const int lane = threadIdx.x & 63;
    const int w = threadIdx.x >> 6;
    const int c = lane >> 3, r = lane & 7;
    const int blk = (int)gridDim.x - 1 - (int)blockIdx.x;  // reversed for L3 reuse
    const int s = blk >> 3;
    const int g = (blk & 7) * 4 + w;
    const int n0 = g * 8;
    const int b = n0 >> 6;
    const int cc0 = n0 & (C - 1);
    const int n = n0 + c;
    const int tbase = s * TQ;

    float yvr[8], yvi[8];
    {
        const float4* cv = (const float4*)(carry + (long)(s * 256 + n) * 8);
        float4 w0 = cv[0], w1 = cv[1], w2 = cv[2], w3 = cv[3];
        yvr[0]=w0.x; yvi[0]=w0.y; yvr[1]=w0.z; yvi[1]=w0.w;
        yvr[2]=w1.x; yvi[2]=w1.y; yvr[3]=w1.z; yvi[3]=w1.w;
        yvr[4]=w2.x; yvi[4]=w2.y; yvr[5]=w2.z; yvi[5]=w2.w;
        yvr[6]=w3.x; yvi[6]=w3.y; yvr[7]=w3.z; yvi[7]=w3.w;
    }

    float4 sa0, sa1, si0, si1; float sxr, sxi;
    float4 ta0, ta1, ti0, ti1; float txr, txi;

#define LOADSET3(t, A0, A1, I0, I1, XR, XI)                                    \
    {                                                                          \
        const int fb = (b * L + (t)) * C + cc0;                                \
        const float4* pA = (const float4*)(Are + (long)fb * 64) + lane * 2;    \
        const float4* pI = (const float4*)(Aim + (long)fb * 64) + lane * 2;    \
        A0 = pA[0]; A1 = pA[1]; I0 = pI[0]; I1 = pI[1];                        \
        XR = Xre[(long)fb * 8 + lane]; XI = Xim[(long)fb * 8 + lane];          \
    }

#define FIX_STEP(A0, A1, I0, I1, XR_, XI_, t)                                  \
    {                                                                          \
        float nr0 = (XR_), ni0 = (XI_), nr1 = 0.f, ni1 = 0.f;                  \
        nr0 += A0.x * yvr[0] - I0.x * yvi[0];                                  \
        ni0 += A0.x * yvi[0] + I0.x * yvr[0];                                  \
        nr1 += A0.y * yvr[1] - I0.y * yvi[1];                                  \
        ni1 += A0.y * yvi[1] + I0.y * yvr[1];                                  \
        nr0 += A0.z * yvr[2] - I0.z * yvi[2];                                  \
        ni0 += A0.z * yvi[2] + I0.z * yvr[2];                                  \
        nr1 += A0.w * yvr[3] - I0.w * yvi[3];                                  \
        ni1 += A0.w * yvi[3] + I0.w * yvr[3];                                  \
        nr0 += A1.x * yvr[4] - I1.x * yvi[4];                                  \
        ni0 += A1.x * yvi[4] + I1.x * yvr[4];                                  \
        nr1 += A1.y * yvr[5] - I1.y * yvi[5];                                  \
        ni1 += A1.y * yvi[5] + I1.y * yvr[5];                                  \
        nr0 += A1.z * yvr[6] - I1.z * yvi[6];                                  \
        ni0 += A1.z * yvi[6] + I1.z * yvr[6];                                  \
        nr1 += A1.w * yvr[7] - I1.w * yvi[7];                                  \
        ni1 += A1.w * yvi[7] + I1.w * yvr[7];                                  \
        const float nr = nr0 + nr1, ni = ni0 + ni1;                            \
        const int fb = (b * L + (t)) * C + cc0;                                \
        out[(long)fb * 8 + lane] = make_float2(nr, ni);                        \
        _Pragma("unroll")                                                      \
        for (int k = 0; k < 8; ++k) {                                          \
            yvr[k] = __shfl(nr, (c << 3) + k, 64);                             \
            yvi[k] = __shfl(ni, (c << 3) + k, 64);                             \
        }                                                                      \
    }

    LOADSET3(tbase + 0, sa0, sa1, si0, si1, sxr, sxi);
    LOADSET3(tbase + 1, ta0, ta1, ti0, ti1, txr, txi);

#pragma unroll 1
    for (int tt = 0; tt < TQ; tt += 2) {
        float4 A0 = sa0, A1 = sa1, I0 = si0, I1 = si1;
        float XR = sxr, XI = sxi;
        if (tt + 2 < TQ) LOADSET3(tbase + tt + 2, sa0, sa1, si0, si1, sxr, sxi);
        FIX_STEP(A0, A1, I0, I1, XR, XI, tbase + tt);
        float4 B0 = ta0, B1 = ta1, J0 = ti0, J1 = ti1;
        float YR = txr, YI = txi;
        if (tt + 3 < TQ) LOADSET3(tbase + tt + 3, ta0, ta1, ti0, ti1, txr, txi);
        FIX_STEP(B0, B1, J0, J1, YR, YI, tbase + tt + 1);
    }
}

extern "C" void kernel_launch(void* const* d_in, const int* in_sizes, int n_in,
                              void* d_out, int out_size, void* d_ws, size_t ws_size,
                              hipStream_t stream)
{
    const float* Are = (const float*)d_in[0];
    const float* Aim = (const float*)d_in[1];
    const float* Xre = (const float*)d_in[2];
    const float* Xim = (const float*)d_in[3];
    float2* out = (float2*)d_out;

    float2* sumP  = (float2*)d_ws;                    // S*NCH*64 float2 (16 MB)
    float2* sumQ  = sumP + (long)S * NCH * 64;        // S*NCH*8  float2 (2 MB)
    float2* carry = sumQ + (long)S * NCH * 8;         // S*NCH*8  float2 (2 MB)

    k_summary<<<(S * GRP) / 4, 256, 0, stream>>>(Are, Aim, Xre, Xim, sumP, sumQ);
    k_carry<<<NCH / 8, 64, 0, stream>>>(sumP, sumQ, carry);
    k_fixup<<<(S * GRP) / 4, 256, 0, stream>>>(Are, Aim, Xre, Xim, carry, out);
}

// Round 4
// 409.943 us; speedup vs baseline: 1.1128x; 1.1128x over previous
//
#include <hip/hip_runtime.h>

#define B 4
#define L 2048
#define C 64
#define R 8
#define NCH (B * C)      // 256 chains
#define TQ 16            // timesteps per chunk
#define S (L / TQ)       // 128 chunks per chain
#define GRP (NCH / 8)    // 32 chain-groups (8 chains per wave)

// Workspace (float2): sumP [S][NCH][8][8] (16 MB), sumQ [S][NCH][8] (2 MB),
// carry [S][NCH][8] (2 MB).
//
// Lane mapping: lane = c*8 + r (c = chain-in-group, r = row).
//
// k_summary LDS layout (per wave, per buffer; byte offsets):
//   A_re row k of chain c : 272*c + 32*k   (chain stride 17 float4 = 272 B)
//   A_im row k of chain c : 2176 + 272*c + 32*k
//   X    chain c          : 4352 + 80*c    (re at +4r, im at +32+4r)
//   buffer stride 4992 B, 2 buffers/wave, 4 waves -> 39936 B/WG (4 WG/CU).
// Bank math: A-read addr word = 68c+8k -> bank 4c+8k, distinct per chain ->
// conflict-free, AND the read offset is (32k [+2176]) = compile-time
// immediate off ONE per-lane base VGPR (272c). Zero per-step LDS addr VALU.
// (The old XOR swizzle was conflict-free too, but forced a per-lane address
// compute for every access — ~600 overhead VALU/step, the measured 39%-
// VALUBusy wall shared by rounds 0 and 2.)

// ---------------- Phase 1: chunk summaries ----------------
__global__ __launch_bounds__(256) void k_summary(
    const float* __restrict__ Are, const float* __restrict__ Aim,
    const float* __restrict__ Xre, const float* __restrict__ Xim,
    float2* __restrict__ sumP, float2* __restrict__ sumQ)
{
    __shared__ __align__(16) float sm[4 * 2 * 1248];   // 39936 B
    const int lane = threadIdx.x & 63;
    const int w = __builtin_amdgcn_readfirstlane((int)(threadIdx.x >> 6));
    const int c = lane >> 3, r = lane & 7;
    const int s = blockIdx.x >> 3;            // chunk
    const int g = (blockIdx.x & 7) * 4 + w;   // chain-group (4 per WG)
    const int n0 = g * 8;
    const int b = n0 >> 6;
    const int cc0 = n0 & (C - 1);
    const int n = n0 + c;
    const int tbase = s * TQ;

    char* const smw = ((char*)sm) + w * 9984;          // wave's LDS base
    char* const wrA = smw + 272 * c + 32 * r;          // staging write base (A)
    char* const wrX = smw + 4352 + 80 * c + 4 * r;     // staging write base (X)
    const char* const rdA = smw + 272 * c;             // read base (A)
    const char* const rdX = smw + 4352 + 80 * c;       // read base (X)

    // hand-rolled global pointers, decremented once per step
    const int fb0 = (b * L + (tbase + TQ - 1)) * C + cc0;
    const float* pA  = Are + (long)fb0 * 64 + lane * 8;
    const float* pI  = Aim + (long)fb0 * 64 + lane * 8;
    const float* pXr = Xre + (long)fb0 * 8 + lane;
    const float* pXi = Xim + (long)fb0 * 8 + lane;

    float Pre[8], Pim[8], Nre[8], Nim[8];
#pragma unroll
    for (int k = 0; k < 8; ++k) { Pre[k] = (k == r) ? 1.f : 0.f; Pim[k] = 0.f; }
    float qre = 0.f, qim = 0.f;

    float4 sa0, sa1, si0, si1; float sxr, sxi;   // pipeline set 0
    float4 ta0, ta1, ti0, ti1; float txr, txi;   // pipeline set 1

#define SLOAD(A0, A1, I0, I1, XR, XI)                                          \
    {                                                                          \
        A0 = *(const float4*)pA; A1 = *(const float4*)(pA + 4);                \
        I0 = *(const float4*)pI; I1 = *(const float4*)(pI + 4);                \
        XR = *pXr; XI = *pXi;                                                  \
        pA -= 4096; pI -= 4096; pXr -= 512; pXi -= 512;                        \
    }

#define SSTAGE(BUF, A0, A1, I0, I1, XR, XI)                                    \
    {                                                                          \
        *(float4*)(wrA + (BUF)) = A0;                                          \
        *(float4*)(wrA + (BUF) + 16) = A1;                                     \
        *(float4*)(wrA + (BUF) + 2176) = I0;                                   \
        *(float4*)(wrA + (BUF) + 2176 + 16) = I1;                              \
        *(float*)(wrX + (BUF)) = XR;                                           \
        *(float*)(wrX + (BUF) + 32) = XI;                                      \
    }

// D = S @ A_t ; q += S @ x_t.  All LDS reads: immediate offsets off rdA/rdX.
#define SCOMP(BUF, SRe, SIm, DRe, DIm)                                         \
    {                                                                          \
        float xr[8], xi[8];                                                    \
        *(float4*)&xr[0] = *(const float4*)(rdX + (BUF));                      \
        *(float4*)&xr[4] = *(const float4*)(rdX + (BUF) + 16);                 \
        *(float4*)&xi[0] = *(const float4*)(rdX + (BUF) + 32);                 \
        *(float4*)&xi[4] = *(const float4*)(rdX + (BUF) + 48);                 \
        _Pragma("unroll")                                                      \
        for (int k = 0; k < 8; ++k) {                                          \
            qre += SRe[k] * xr[k] - SIm[k] * xi[k];                            \
            qim += SRe[k] * xi[k] + SIm[k] * xr[k];                            \
        }                                                                      \
        _Pragma("unroll")                                                      \
        for (int j = 0; j < 8; ++j) { DRe[j] = 0.f; DIm[j] = 0.f; }            \
        _Pragma("unroll")                                                      \
        for (int k = 0; k < 8; ++k) {                                          \
            float er[8], ei[8];                                                \
            *(float4*)&er[0] = *(const float4*)(rdA + (BUF) + 32 * k);         \
            *(float4*)&er[4] = *(const float4*)(rdA + (BUF) + 32 * k + 16);    \
            *(float4*)&ei[0] = *(const float4*)(rdA + (BUF) + 2176 + 32 * k);  \
            *(float4*)&ei[4] = *(const float4*)(rdA + (BUF) + 2192 + 32 * k);  \
            const float pr = SRe[k], pi = SIm[k];                              \
            _Pragma("unroll")                                                  \
            for (int j = 0; j < 8; ++j) {                                      \
                DRe[j] += pr * er[j] - pi * ei[j];                             \
                DIm[j] += pr * ei[j] + pi * er[j];                             \
            }                                                                  \
        }                                                                      \
    }

    SLOAD(sa0, sa1, si0, si1, sxr, sxi);   // t = tbase+15
    SLOAD(ta0, ta1, ti0, ti1, txr, txi);   // t = tbase+14

#pragma unroll 1
    for (int tt = TQ - 1; tt >= 1; tt -= 2) {
        SSTAGE(0, sa0, sa1, si0, si1, sxr, sxi);
        if (tt >= 3) SLOAD(sa0, sa1, si0, si1, sxr, sxi);
        SCOMP(0, Pre, Pim, Nre, Nim);
        SSTAGE(4992, ta0, ta1, ti0, ti1, txr, txi);
        if (tt >= 3) SLOAD(ta0, ta1, ti0, ti1, txr, txi);
        SCOMP(4992, Nre, Nim, Pre, Pim);
    }
    // 16 steps (even) -> result lives in Pre/Pim

    float4* gp = (float4*)(sumP + ((long)(s * 256 + n) * 8 + r) * 8);
    gp[0] = make_float4(Pre[0], Pim[0], Pre[1], Pim[1]);
    gp[1] = make_float4(Pre[2], Pim[2], Pre[3], Pim[3]);
    gp[2] = make_float4(Pre[4], Pim[4], Pre[5], Pim[5]);
    gp[3] = make_float4(Pre[6], Pim[6], Pre[7], Pim[7]);
    sumQ[(long)(s * 256 + n) * 8 + r] = make_float2(qre, qim);
}

// ---------------- Phase 2: carry scan over chunks ----------------
// 4-deep prefetch ring: depth-1 left ~450 cy/iter of exposed L3 latency on
// this 32-wave serial kernel.
__global__ __launch_bounds__(64) void k_carry(
    const float2* __restrict__ sumP, const float2* __restrict__ sumQ,
    float2* __restrict__ carry)
{
    const int lane = threadIdx.x;
    const int c = lane >> 3, r = lane & 7;
    const int n = blockIdx.x * 8 + c;
    const long base2 = (long)n * 8;

    float yr = 0.f, yi = 0.f;

    float4 A0,A1,A2,A3, B0,B1,B2,B3, C0,C1,C2,C3, D0,D1,D2,D3;
    float2 Aq, Bq, Cq, Dq;

#define CLOAD(P0,P1,P2,P3,QV,SS)                                               \
    {                                                                          \
        const float4* np = (const float4*)(sumP + (base2 + (long)(SS) * 2048 + r) * 8); \
        P0 = np[0]; P1 = np[1]; P2 = np[2]; P3 = np[3];                        \
        QV = sumQ[base2 + (long)(SS) * 2048 + r];                              \
    }

#define CSTEP(P0,P1,P2,P3,QV,SS)                                               \
    {                                                                          \
        carry[base2 + (long)(SS) * 2048 + r] = make_float2(yr, yi);            \
        float4 w0 = P0, w1 = P1, w2 = P2, w3 = P3;                             \
        float2 qs = QV;                                                        \
        if ((SS) + 4 < S) CLOAD(P0,P1,P2,P3,QV,(SS) + 4);                      \
        float yvr[8], yvi[8];                                                  \
        _Pragma("unroll")                                                      \
        for (int k = 0; k < 8; ++k) {                                          \
            yvr[k] = __shfl(yr, (c << 3) + k, 64);                             \
            yvi[k] = __shfl(yi, (c << 3) + k, 64);                             \
        }                                                                      \
        float prr[8], pri[8];                                                  \
        prr[0]=w0.x; pri[0]=w0.y; prr[1]=w0.z; pri[1]=w0.w;                    \
        prr[2]=w1.x; pri[2]=w1.y; prr[3]=w1.z; pri[3]=w1.w;                    \
        prr[4]=w2.x; pri[4]=w2.y; prr[5]=w2.z; pri[5]=w2.w;                    \
        prr[6]=w3.x; pri[6]=w3.y; prr[7]=w3.z; pri[7]=w3.w;                    \
        float nr0 = qs.x, ni0 = qs.y, nr1 = 0.f, ni1 = 0.f;                    \
        _Pragma("unroll")                                                      \
        for (int k = 0; k < 8; k += 2) {                                       \
            nr0 += prr[k] * yvr[k] - pri[k] * yvi[k];                          \
            ni0 += prr[k] * yvi[k] + pri[k] * yvr[k];                          \
            nr1 += prr[k+1] * yvr[k+1] - pri[k+1] * yvi[k+1];                  \
            ni1 += prr[k+1] * yvi[k+1] + pri[k+1] * yvr[k+1];                  \
        }                                                                      \
        yr = nr0 + nr1; yi = ni0 + ni1;                                        \
    }

    CLOAD(A0,A1,A2,A3,Aq, 0);
    CLOAD(B0,B1,B2,B3,Bq, 1);
    CLOAD(C0,C1,C2,C3,Cq, 2);
    CLOAD(D0,D1,D2,D3,Dq, 3);

#pragma unroll 1
    for (int ss = 0; ss < S; ss += 4) {
        CSTEP(A0,A1,A2,A3,Aq, ss);
        CSTEP(B0,B1,B2,B3,Bq, ss + 1);
        CSTEP(C0,C1,C2,C3,Cq, ss + 2);
        CSTEP(D0,D1,D2,D3,Dq, ss + 3);
    }
}

// ---------------- Phase 3: fixup + output ----------------
// Lane (c,r) only needs its OWN row r of A_t (register prefetch, no LDS);
// carry broadcast via __shfl.
__global__ __launch_bounds__(256) void k_fixup(
    const float* __restrict__ Are, const float* __restrict__ Aim,
    const float* __restrict__ Xre, const float* __restrict__ Xim,
    const float2* __restrict__ carry, float2* __restrict__ out)
{
    const int lane = threadIdx.x & 63;
    const int w = threadIdx.x >> 6;
    const int c = lane >> 3, r = lane & 7;
    const int blk = (int)gridDim.x - 1 - (int)blockIdx.x;  // reversed for L3 reuse
    const int s = blk >> 3;
    const int g = (blk & 7) * 4 + w;
    const int n0 = g * 8;
    const int b = n0 >> 6;
    const int cc0 = n0 & (C - 1);
    const int n = n0 + c;
    const int tbase = s * TQ;

    float yvr[8], yvi[8];
    {
        const float4* cv = (const float4*)(carry + (long)(s * 256 + n) * 8);
        float4 w0 = cv[0], w1 = cv[1], w2 = cv[2], w3 = cv[3];
        yvr[0]=w0.x; yvi[0]=w0.y; yvr[1]=w0.z; yvi[1]=w0.w;
        yvr[2]=w1.x; yvi[2]=w1.y; yvr[3]=w1.z; yvi[3]=w1.w;
        yvr[4]=w2.x; yvi[4]=w2.y; yvr[5]=w2.z; yvi[5]=w2.w;
        yvr[6]=w3.x; yvi[6]=w3.y; yvr[7]=w3.z; yvi[7]=w3.w;
    }

    float4 sa0, sa1, si0, si1; float sxr, sxi;
    float4 ta0, ta1, ti0, ti1; float txr, txi;

#define LOADSET3(t, A0, A1, I0, I1, XR, XI)                                    \
    {                                                                          \
        const int fb = (b * L + (t)) * C + cc0;                                \
        const float4* pA = (const float4*)(Are + (long)fb * 64) + lane * 2;    \
        const float4* pI = (const float4*)(Aim + (long)fb * 64) + lane * 2;    \
        A0 = pA[0]; A1 = pA[1]; I0 = pI[0]; I1 = pI[1];                        \
        XR = Xre[(long)fb * 8 + lane]; XI = Xim[(long)fb * 8 + lane];          \
    }

#define FIX_STEP(A0, A1, I0, I1, XR_, XI_, t)                                  \
    {                                                                          \
        float nr0 = (XR_), ni0 = (XI_), nr1 = 0.f, ni1 = 0.f;                  \
        nr0 += A0.x * yvr[0] - I0.x * yvi[0];                                  \
        ni0 += A0.x * yvi[0] + I0.x * yvr[0];                                  \
        nr1 += A0.y * yvr[1] - I0.y * yvi[1];                                  \
        ni1 += A0.y * yvi[1] + I0.y * yvr[1];                                  \
        nr0 += A0.z * yvr[2] - I0.z * yvi[2];                                  \
        ni0 += A0.z * yvi[2] + I0.z * yvr[2];                                  \
        nr1 += A0.w * yvr[3] - I0.w * yvi[3];                                  \
        ni1 += A0.w * yvi[3] + I0.w * yvr[3];                                  \
        nr0 += A1.x * yvr[4] - I1.x * yvi[4];                                  \
        ni0 += A1.x * yvi[4] + I1.x * yvr[4];                                  \
        nr1 += A1.y * yvr[5] - I1.y * yvi[5];                                  \
        ni1 += A1.y * yvi[5] + I1.y * yvr[5];                                  \
        nr0 += A1.z * yvr[6] - I1.z * yvi[6];                                  \
        ni0 += A1.z * yvi[6] + I1.z * yvr[6];                                  \
        nr1 += A1.w * yvr[7] - I1.w * yvi[7];                                  \
        ni1 += A1.w * yvi[7] + I1.w * yvr[7];                                  \
        const float nr = nr0 + nr1, ni = ni0 + ni1;                            \
        const int fb = (b * L + (t)) * C + cc0;                                \
        out[(long)fb * 8 + lane] = make_float2(nr, ni);                        \
        _Pragma("unroll")                                                      \
        for (int k = 0; k < 8; ++k) {                                          \
            yvr[k] = __shfl(nr, (c << 3) + k, 64);                             \
            yvi[k] = __shfl(ni, (c << 3) + k, 64);                             \
        }                                                                      \
    }

    LOADSET3(tbase + 0, sa0, sa1, si0, si1, sxr, sxi);
    LOADSET3(tbase + 1, ta0, ta1, ti0, ti1, txr, txi);

#pragma unroll 1
    for (int tt = 0; tt < TQ; tt += 2) {
        float4 A0 = sa0, A1 = sa1, I0 = si0, I1 = si1;
        float XR = sxr, XI = sxi;
        if (tt + 2 < TQ) LOADSET3(tbase + tt + 2, sa0, sa1, si0, si1, sxr, sxi);
        FIX_STEP(A0, A1, I0, I1, XR, XI, tbase + tt);
        float4 B0 = ta0, B1 = ta1, J0 = ti0, J1 = ti1;
        float YR = txr, YI = txi;
        if (tt + 3 < TQ) LOADSET3(tbase + tt + 3, ta0, ta1, ti0, ti1, txr, txi);
        FIX_STEP(B0, B1, J0, J1, YR, YI, tbase + tt + 1);
    }
}

extern "C" void kernel_launch(void* const* d_in, const int* in_sizes, int n_in,
                              void* d_out, int out_size, void* d_ws, size_t ws_size,
                              hipStream_t stream)
{
    const float* Are = (const float*)d_in[0];
    const float* Aim = (const float*)d_in[1];
    const float* Xre = (const float*)d_in[2];
    const float* Xim = (const float*)d_in[3];
    float2* out = (float2*)d_out;

    float2* sumP  = (float2*)d_ws;                    // S*NCH*64 float2 (16 MB)
    float2* sumQ  = sumP + (long)S * NCH * 64;        // S*NCH*8  float2 (2 MB)
    float2* carry = sumQ + (long)S * NCH * 8;         // S*NCH*8  float2 (2 MB)

    k_summary<<<(S * GRP) / 4, 256, 0, stream>>>(Are, Aim, Xre, Xim, sumP, sumQ);
    k_carry<<<NCH / 8, 64, 0, stream>>>(sumP, sumQ, carry);
    k_fixup<<<(S * GRP) / 4, 256, 0, stream>>>(Are, Aim, Xre, Xim, carry, out);
}

// Round 6
// 409.038 us; speedup vs baseline: 1.1153x; 1.0022x over previous
//
#include <hip/hip_runtime.h>

#define B 4
#define L 2048
#define C 64
#define R 8
#define NCH (B * C)      // 256 chains
#define TQ 16            // timesteps per chunk
#define S (L / TQ)       // 128 chunks per chain
#define GRP (NCH / 8)    // 32 chain-groups (8 chains per wave)

// Workspace (float2): sumP [S][NCH][8][8] (16 MB), sumQ [S][NCH][8] (2 MB),
// carry [S][NCH][8] (2 MB).
//
// Lane mapping: lane = c*8 + r (c = chain-in-group, r = row).
//
// k_summary LDS layout (per wave, per buffer; byte offsets):
//   A_re row k of chain c : 272*c + 32*k   (chain stride 17 float4 = 272 B)
//   A_im row k of chain c : 2176 + 272*c + 32*k
//   X    chain c          : 4352 + 80*c    (re at +4r, im at +32+4r)
//   buffer stride 4992 B, 2 buffers/wave, 4 waves -> 39936 B/WG (4 WG/CU).
// Conflict-free (verified R4: 2.4e6 conflict cycles, negligible) and all
// per-step LDS addresses are immediates off one per-lane base VGPR.
//
// SCHEDULE (the round-5 change, resubmitted after infra failure):
// 3-stage software pipeline.
//   COMP(b0 = t) ; STAGE(b0 <- t-2) ; LOAD(t-4)
//   COMP(b1 = t-1); STAGE(b1 <- t-3) ; LOAD(t-5)
// - COMP reads data staged one full compute-phase earlier (no same-step
//   LDS write->read round trip; DS ops are in-order per wave, so writing
//   b0 right after reading b0 is WAR-safe).
// - global load -> stage distance is ~2 compute phases (>~1200 cy issue)
//   which covers the ~900 cy HBM latency. R0/R2/R4 all had depth-1
//   (~600 cy cover) and all sat at the same ~140 us latency wall.

// ---------------- Phase 1: chunk summaries ----------------
__global__ __launch_bounds__(256) void k_summary(
    const float* __restrict__ Are, const float* __restrict__ Aim,
    const float* __restrict__ Xre, const float* __restrict__ Xim,
    float2* __restrict__ sumP, float2* __restrict__ sumQ)
{
    __shared__ __align__(16) float sm[4 * 2 * 1248];   // 39936 B
    const int lane = threadIdx.x & 63;
    const int w = __builtin_amdgcn_readfirstlane((int)(threadIdx.x >> 6));
    const int c = lane >> 3, r = lane & 7;
    const int s = blockIdx.x >> 3;            // chunk
    const int g = (blockIdx.x & 7) * 4 + w;   // chain-group (4 per WG)
    const int n0 = g * 8;
    const int b = n0 >> 6;
    const int cc0 = n0 & (C - 1);
    const int n = n0 + c;
    const int tbase = s * TQ;

    char* const smw = ((char*)sm) + w * 9984;          // wave's LDS base
    char* const wrA = smw + 272 * c + 32 * r;          // staging write base (A)
    char* const wrX = smw + 4352 + 80 * c + 4 * r;     // staging write base (X)
    const char* const rdA = smw + 272 * c;             // read base (A)
    const char* const rdX = smw + 4352 + 80 * c;       // read base (X)

    // hand-rolled global pointers, decremented once per SLOAD (one t step)
    const int fb0 = (b * L + (tbase + TQ - 1)) * C + cc0;
    const float* pA  = Are + (long)fb0 * 64 + lane * 8;
    const float* pI  = Aim + (long)fb0 * 64 + lane * 8;
    const float* pXr = Xre + (long)fb0 * 8 + lane;
    const float* pXi = Xim + (long)fb0 * 8 + lane;

    float Pre[8], Pim[8], Nre[8], Nim[8];
#pragma unroll
    for (int k = 0; k < 8; ++k) { Pre[k] = (k == r) ? 1.f : 0.f; Pim[k] = 0.f; }
    float qre = 0.f, qim = 0.f;

    float4 sa0, sa1, si0, si1; float sxr, sxi;   // pipeline set 0
    float4 ta0, ta1, ti0, ti1; float txr, txi;   // pipeline set 1

#define SLOAD(A0, A1, I0, I1, XR, XI)                                          \
    {                                                                          \
        A0 = *(const float4*)pA; A1 = *(const float4*)(pA + 4);                \
        I0 = *(const float4*)pI; I1 = *(const float4*)(pI + 4);                \
        XR = *pXr; XI = *pXi;                                                  \
        pA -= 4096; pI -= 4096; pXr -= 512; pXi -= 512;                        \
    }

#define SSTAGE(BUF, A0, A1, I0, I1, XR, XI)                                    \
    {                                                                          \
        *(float4*)(wrA + (BUF)) = A0;                                          \
        *(float4*)(wrA + (BUF) + 16) = A1;                                     \
        *(float4*)(wrA + (BUF) + 2176) = I0;                                   \
        *(float4*)(wrA + (BUF) + 2176 + 16) = I1;                              \
        *(float*)(wrX + (BUF)) = XR;                                           \
        *(float*)(wrX + (BUF) + 32) = XI;                                      \
    }

// D = S @ A_t ; q += S @ x_t.  All LDS reads: immediate offsets off rdA/rdX.
#define SCOMP(BUF, SRe, SIm, DRe, DIm)                                         \
    {                                                                          \
        float xr[8], xi[8];                                                    \
        *(float4*)&xr[0] = *(const float4*)(rdX + (BUF));                      \
        *(float4*)&xr[4] = *(const float4*)(rdX + (BUF) + 16);                 \
        *(float4*)&xi[0] = *(const float4*)(rdX + (BUF) + 32);                 \
        *(float4*)&xi[4] = *(const float4*)(rdX + (BUF) + 48);                 \
        _Pragma("unroll")                                                      \
        for (int k = 0; k < 8; ++k) {                                          \
            qre += SRe[k] * xr[k] - SIm[k] * xi[k];                            \
            qim += SRe[k] * xi[k] + SIm[k] * xr[k];                            \
        }                                                                      \
        _Pragma("unroll")                                                      \
        for (int j = 0; j < 8; ++j) { DRe[j] = 0.f; DIm[j] = 0.f; }            \
        _Pragma("unroll")                                                      \
        for (int k = 0; k < 8; ++k) {                                          \
            float er[8], ei[8];                                                \
            *(float4*)&er[0] = *(const float4*)(rdA + (BUF) + 32 * k);         \
            *(float4*)&er[4] = *(const float4*)(rdA + (BUF) + 32 * k + 16);    \
            *(float4*)&ei[0] = *(const float4*)(rdA + (BUF) + 2176 + 32 * k);  \
            *(float4*)&ei[4] = *(const float4*)(rdA + (BUF) + 2192 + 32 * k);  \
            const float pr = SRe[k], pi = SIm[k];                              \
            _Pragma("unroll")                                                  \
            for (int j = 0; j < 8; ++j) {                                      \
                DRe[j] += pr * er[j] - pi * ei[j];                             \
                DIm[j] += pr * ei[j] + pi * er[j];                             \
            }                                                                  \
        }                                                                      \
    }

    // ---- prologue: fill both LDS buffers and both register sets ----
    SLOAD(sa0, sa1, si0, si1, sxr, sxi);        // t15 -> regs
    SLOAD(ta0, ta1, ti0, ti1, txr, txi);        // t14 -> regs
    SSTAGE(0, sa0, sa1, si0, si1, sxr, sxi);    // buf0 <- t15
    SLOAD(sa0, sa1, si0, si1, sxr, sxi);        // t13 -> regs
    SSTAGE(4992, ta0, ta1, ti0, ti1, txr, txi); // buf1 <- t14
    SLOAD(ta0, ta1, ti0, ti1, txr, txi);        // t12 -> regs

    // ---- steady state: tt = 15,13,11,9,7,5 (loads run down to t=0) ----
#pragma unroll 1
    for (int tt = TQ - 1; tt >= 5; tt -= 2) {
        SCOMP(0, Pre, Pim, Nre, Nim);                 // compute t = tt
        SSTAGE(0, sa0, sa1, si0, si1, sxr, sxi);      // buf0 <- tt-2
        SLOAD(sa0, sa1, si0, si1, sxr, sxi);          // load tt-4
        SCOMP(4992, Nre, Nim, Pre, Pim);              // compute t = tt-1
        SSTAGE(4992, ta0, ta1, ti0, ti1, txr, txi);   // buf1 <- tt-3
        SLOAD(ta0, ta1, ti0, ti1, txr, txi);          // load tt-5
    }
    // ---- peeled iteration tt=3 (no more loads) ----
    SCOMP(0, Pre, Pim, Nre, Nim);                     // t=3
    SSTAGE(0, sa0, sa1, si0, si1, sxr, sxi);          // buf0 <- t=1
    SCOMP(4992, Nre, Nim, Pre, Pim);                  // t=2
    SSTAGE(4992, ta0, ta1, ti0, ti1, txr, txi);       // buf1 <- t=0
    // ---- tail ----
    SCOMP(0, Pre, Pim, Nre, Nim);                     // t=1
    SCOMP(4992, Nre, Nim, Pre, Pim);                  // t=0

    float4* gp = (float4*)(sumP + ((long)(s * 256 + n) * 8 + r) * 8);
    gp[0] = make_float4(Pre[0], Pim[0], Pre[1], Pim[1]);
    gp[1] = make_float4(Pre[2], Pim[2], Pre[3], Pim[3]);
    gp[2] = make_float4(Pre[4], Pim[4], Pre[5], Pim[5]);
    gp[3] = make_float4(Pre[6], Pim[6], Pre[7], Pim[7]);
    sumQ[(long)(s * 256 + n) * 8 + r] = make_float2(qre, qim);
}

// ---------------- Phase 2: carry scan over chunks ----------------
__global__ __launch_bounds__(64) void k_carry(
    const float2* __restrict__ sumP, const float2* __restrict__ sumQ,
    float2* __restrict__ carry)
{
    const int lane = threadIdx.x;
    const int c = lane >> 3, r = lane & 7;
    const int n = blockIdx.x * 8 + c;
    const long base2 = (long)n * 8;

    float yr = 0.f, yi = 0.f;

    float4 A0,A1,A2,A3, B0,B1,B2,B3, C0,C1,C2,C3, D0,D1,D2,D3;
    float2 Aq, Bq, Cq, Dq;

#define CLOAD(P0,P1,P2,P3,QV,SS)                                               \
    {                                                                          \
        const float4* np = (const float4*)(sumP + (base2 + (long)(SS) * 2048 + r) * 8); \
        P0 = np[0]; P1 = np[1]; P2 = np[2]; P3 = np[3];                        \
        QV = sumQ[base2 + (long)(SS) * 2048 + r];                              \
    }

#define CSTEP(P0,P1,P2,P3,QV,SS)                                               \
    {                                                                          \
        carry[base2 + (long)(SS) * 2048 + r] = make_float2(yr, yi);            \
        float4 w0 = P0, w1 = P1, w2 = P2, w3 = P3;                             \
        float2 qs = QV;                                                        \
        if ((SS) + 4 < S) CLOAD(P0,P1,P2,P3,QV,(SS) + 4);                      \
        float yvr[8], yvi[8];                                                  \
        _Pragma("unroll")                                                      \
        for (int k = 0; k < 8; ++k) {                                          \
            yvr[k] = __shfl(yr, (c << 3) + k, 64);                             \
            yvi[k] = __shfl(yi, (c << 3) + k, 64);                             \
        }                                                                      \
        float prr[8], pri[8];                                                  \
        prr[0]=w0.x; pri[0]=w0.y; prr[1]=w0.z; pri[1]=w0.w;                    \
        prr[2]=w1.x; pri[2]=w1.y; prr[3]=w1.z; pri[3]=w1.w;                    \
        prr[4]=w2.x; pri[4]=w2.y; prr[5]=w2.z; pri[5]=w2.w;                    \
        prr[6]=w3.x; pri[6]=w3.y; prr[7]=w3.z; pri[7]=w3.w;                    \
        float nr0 = qs.x, ni0 = qs.y, nr1 = 0.f, ni1 = 0.f;                    \
        _Pragma("unroll")                                                      \
        for (int k = 0; k < 8; k += 2) {                                       \
            nr0 += prr[k] * yvr[k] - pri[k] * yvi[k];                          \
            ni0 += prr[k] * yvi[k] + pri[k] * yvr[k];                          \
            nr1 += prr[k+1] * yvr[k+1] - pri[k+1] * yvi[k+1];                  \
            ni1 += prr[k+1] * yvi[k+1] + pri[k+1] * yvr[k+1];                  \
        }                                                                      \
        yr = nr0 + nr1; yi = ni0 + ni1;                                        \
    }

    CLOAD(A0,A1,A2,A3,Aq, 0);
    CLOAD(B0,B1,B2,B3,Bq, 1);
    CLOAD(C0,C1,C2,C3,Cq, 2);
    CLOAD(D0,D1,D2,D3,Dq, 3);

#pragma unroll 1
    for (int ss = 0; ss < S; ss += 4) {
        CSTEP(A0,A1,A2,A3,Aq, ss);
        CSTEP(B0,B1,B2,B3,Bq, ss + 1);
        CSTEP(C0,C1,C2,C3,Cq, ss + 2);
        CSTEP(D0,D1,D2,D3,Dq, ss + 3);
    }
}

// ---------------- Phase 3: fixup + output ----------------
// Lane (c,r) only needs its OWN row r of A_t; carry broadcast via __shfl.
// 4-deep register prefetch ring (was depth 2) so the load->use distance
// covers HBM latency.
__global__ __launch_bounds__(256) void k_fixup(
    const float* __restrict__ Are, const float* __restrict__ Aim,
    const float* __restrict__ Xre, const float* __restrict__ Xim,
    const float2* __restrict__ carry, float2* __restrict__ out)
{
    const int lane = threadIdx.x & 63;
    const int w = threadIdx.x >> 6;
    const int c = lane >> 3, r = lane & 7;
    const int blk = (int)gridDim.x - 1 - (int)blockIdx.x;  // reversed for L3 reuse
    const int s = blk >> 3;
    const int g = (blk & 7) * 4 + w;
    const int n0 = g * 8;
    const int b = n0 >> 6;
    const int cc0 = n0 & (C - 1);
    const int n = n0 + c;
    const int tbase = s * TQ;

    float yvr[8], yvi[8];
    {
        const float4* cv = (const float4*)(carry + (long)(s * 256 + n) * 8);
        float4 w0 = cv[0], w1 = cv[1], w2 = cv[2], w3 = cv[3];
        yvr[0]=w0.x; yvi[0]=w0.y; yvr[1]=w0.z; yvi[1]=w0.w;
        yvr[2]=w1.x; yvi[2]=w1.y; yvr[3]=w1.z; yvi[3]=w1.w;
        yvr[4]=w2.x; yvi[4]=w2.y; yvr[5]=w2.z; yvi[5]=w2.w;
        yvr[6]=w3.x; yvi[6]=w3.y; yvr[7]=w3.z; yvi[7]=w3.w;
    }

    float4 Ua0,Ua1,Ui0,Ui1; float Uxr,Uxi;   // ring slot 0
    float4 Va0,Va1,Vi0,Vi1; float Vxr,Vxi;   // ring slot 1
    float4 Wa0,Wa1,Wi0,Wi1; float Wxr,Wxi;   // ring slot 2
    float4 Za0,Za1,Zi0,Zi1; float Zxr,Zxi;   // ring slot 3

#define FLOAD(t, A0, A1, I0, I1, XR, XI)                                       \
    {                                                                          \
        const int fb = (b * L + (t)) * C + cc0;                                \
        const float4* pA = (const float4*)(Are + (long)fb * 64) + lane * 2;    \
        const float4* pI = (const float4*)(Aim + (long)fb * 64) + lane * 2;    \
        A0 = pA[0]; A1 = pA[1]; I0 = pI[0]; I1 = pI[1];                        \
        XR = Xre[(long)fb * 8 + lane]; XI = Xim[(long)fb * 8 + lane];          \
    }

#define FIX_STEP(A0, A1, I0, I1, XR_, XI_, t)                                  \
    {                                                                          \
        float nr0 = (XR_), ni0 = (XI_), nr1 = 0.f, ni1 = 0.f;                  \
        nr0 += A0.x * yvr[0] - I0.x * yvi[0];                                  \
        ni0 += A0.x * yvi[0] + I0.x * yvr[0];                                  \
        nr1 += A0.y * yvr[1] - I0.y * yvi[1];                                  \
        ni1 += A0.y * yvi[1] + I0.y * yvr[1];                                  \
        nr0 += A0.z * yvr[2] - I0.z * yvi[2];                                  \
        ni0 += A0.z * yvi[2] + I0.z * yvr[2];                                  \
        nr1 += A0.w * yvr[3] - I0.w * yvi[3];                                  \
        ni1 += A0.w * yvi[3] + I0.w * yvr[3];                                  \
        nr0 += A1.x * yvr[4] - I1.x * yvi[4];                                  \
        ni0 += A1.x * yvi[4] + I1.x * yvr[4];                                  \
        nr1 += A1.y * yvr[5] - I1.y * yvi[5];                                  \
        ni1 += A1.y * yvi[5] + I1.y * yvr[5];                                  \
        nr0 += A1.z * yvr[6] - I1.z * yvi[6];                                  \
        ni0 += A1.z * yvi[6] + I1.z * yvr[6];                                  \
        nr1 += A1.w * yvr[7] - I1.w * yvi[7];                                  \
        ni1 += A1.w * yvi[7] + I1.w * yvr[7];                                  \
        const float nr = nr0 + nr1, ni = ni0 + ni1;                            \
        const int fb = (b * L + (t)) * C + cc0;                                \
        out[(long)fb * 8 + lane] = make_float2(nr, ni);                        \
        _Pragma("unroll")                                                      \
        for (int k = 0; k < 8; ++k) {                                          \
            yvr[k] = __shfl(nr, (c << 3) + k, 64);                             \
            yvi[k] = __shfl(ni, (c << 3) + k, 64);                             \
        }                                                                      \
    }

    FLOAD(tbase + 0, Ua0,Ua1,Ui0,Ui1,Uxr,Uxi);
    FLOAD(tbase + 1, Va0,Va1,Vi0,Vi1,Vxr,Vxi);
    FLOAD(tbase + 2, Wa0,Wa1,Wi0,Wi1,Wxr,Wxi);
    FLOAD(tbase + 3, Za0,Za1,Zi0,Zi1,Zxr,Zxi);

#pragma unroll 1
    for (int tt = 0; tt < TQ; tt += 4) {
        FIX_STEP(Ua0,Ua1,Ui0,Ui1,Uxr,Uxi, tbase + tt);
        if (tt + 4 < TQ) FLOAD(tbase + tt + 4, Ua0,Ua1,Ui0,Ui1,Uxr,Uxi);
        FIX_STEP(Va0,Va1,Vi0,Vi1,Vxr,Vxi, tbase + tt + 1);
        if (tt + 5 < TQ) FLOAD(tbase + tt + 5, Va0,Va1,Vi0,Vi1,Vxr,Vxi);
        FIX_STEP(Wa0,Wa1,Wi0,Wi1,Wxr,Wxi, tbase + tt + 2);
        if (tt + 6 < TQ) FLOAD(tbase + tt + 6, Wa0,Wa1,Wi0,Wi1,Wxr,Wxi);
        FIX_STEP(Za0,Za1,Zi0,Zi1,Zxr,Zxi, tbase + tt + 3);
        if (tt + 7 < TQ) FLOAD(tbase + tt + 7, Za0,Za1,Zi0,Zi1,Zxr,Zxi);
    }
}

extern "C" void kernel_launch(void* const* d_in, const int* in_sizes, int n_in,
                              void* d_out, int out_size, void* d_ws, size_t ws_size,
                              hipStream_t stream)
{
    const float* Are = (const float*)d_in[0];
    const float* Aim = (const float*)d_in[1];
    const float* Xre = (const float*)d_in[2];
    const float* Xim = (const float*)d_in[3];
    float2* out = (float2*)d_out;

    float2* sumP  = (float2*)d_ws;                    // S*NCH*64 float2 (16 MB)
    float2* sumQ  = sumP + (long)S * NCH * 64;        // S*NCH*8  float2 (2 MB)
    float2* carry = sumQ + (long)S * NCH * 8;         // S*NCH*8  float2 (2 MB)

    k_summary<<<(S * GRP) / 4, 256, 0, stream>>>(Are, Aim, Xre, Xim, sumP, sumQ);
    k_carry<<<NCH / 8, 64, 0, stream>>>(sumP, sumQ, carry);
    k_fixup<<<(S * GRP) / 4, 256, 0, stream>>>(Are, Aim, Xre, Xim, carry, out);
}